// Round 7
// baseline (298.408 us; speedup 1.0000x reference)
//
#include <hip/hip_runtime.h>

// WARP loss: B=4096 rows, Y=10000 labels, T=128 negative-candidate trials.
// input [B,Y] f32, target [B,Y] f32 (one-hot), neg_candidates [B,T] i32.
// out[0] = sum over rows of log((Y-1)/num_trials) * (1 - s_pos + s_neg),
// num_trials = 1 + first t with 1 + s_neg_t - s_pos >= 0 (0 contribution if none).
//
// BRANCHLESS full-row scan, one wave per row.
//   Rationale (R1-R6 data): early-exit/segmented/deep-pipeline variants all
//   plateau ~2.5 TB/s effective -- every load-check-maybe-load structure
//   drains vmcnt at each decision. Here pos = sum_j 1{t[j]!=0}*j: 40 groups
//   as 5 statically-unrolled blocks of 8 named uint4 regs (A/B double
//   buffer), 8-16 KB continuously in flight, ZERO data-dependent branches
//   until the final wave-reduce. Same access shape as the 6.8 TB/s fills.
//   Candidates: R5's progressive widening (16 -> 64 -> 48), stage-A gathers
//   prefetched under the scan. Per-row partials; 1-block reduce -> out[0].

constexpr int Yc = 10000;
constexpr int Tc = 128;
constexpr int R4 = 2500;   // uint4 per row (40 KB, 16B-aligned per row)

__global__ __launch_bounds__(256) void warp_fused_kernel(
        const float* __restrict__ input,
        const float* __restrict__ target,
        const int*   __restrict__ neg,
        float* __restrict__ partial,
        int B) {
    const int wave = threadIdx.x >> 6;
    const int lane = threadIdx.x & 63;
    const int row  = blockIdx.x * 4 + wave;
    if (row >= B) return;                      // no barriers in kernel: safe

    const int*   nrow = neg + row * Tc;
    const float* irow = input + (size_t)row * Yc;
    const uint4* trow = reinterpret_cast<const uint4*>(target + (size_t)row * Yc);

    const int cA = nrow[lane & 15];            // trials 0..15 (x4 dup), 1 line

    auto LD  = [&](int g) -> uint4 { return trow[g * 64 + lane]; };  // g<=38: idx<=2495<R4
    auto LDC = [&](int g) -> uint4 {                                  // g==39 overhang
        int i = g * 64 + lane; return trow[i < R4 ? i : R4 - 1];
    };

    int pacc = 0;
    auto PROC = [&](int g, const uint4& v) {
        const int b = 4 * (g * 64 + lane);
        if (v.x) pacc += b;                    // cmp+cndmask+add, no flow change
        if (v.y) pacc += b + 1;
        if (v.z) pacc += b + 2;
        if (v.w) pacc += b + 3;
    };
    auto PROCM = [&](int g, const uint4& v) {  // mask clamped re-reads
        const int idx = g * 64 + lane;
        if (idx < R4) {
            const int b = 4 * idx;
            if (v.x) pacc += b;
            if (v.y) pacc += b + 1;
            if (v.z) pacc += b + 2;
            if (v.w) pacc += b + 3;
        }
    };

    // ---- 40 groups, 5 blocks of 8, A/B named double-buffer ----
    uint4 A0=LD(0),A1=LD(1),A2=LD(2),A3=LD(3),A4=LD(4),A5=LD(5),A6=LD(6),A7=LD(7);
    uint4 B0=LD(8),B1=LD(9),B2=LD(10),B3=LD(11),B4=LD(12),B5=LD(13),B6=LD(14),B7=LD(15);
    const float sA = irow[cA];                 // lands under the scan

    PROC(0,A0); PROC(1,A1); PROC(2,A2); PROC(3,A3);
    PROC(4,A4); PROC(5,A5); PROC(6,A6); PROC(7,A7);
    A0=LD(16); A1=LD(17); A2=LD(18); A3=LD(19);
    A4=LD(20); A5=LD(21); A6=LD(22); A7=LD(23);

    PROC(8,B0); PROC(9,B1); PROC(10,B2); PROC(11,B3);
    PROC(12,B4); PROC(13,B5); PROC(14,B6); PROC(15,B7);
    B0=LD(24); B1=LD(25); B2=LD(26); B3=LD(27);
    B4=LD(28); B5=LD(29); B6=LD(30); B7=LD(31);

    PROC(16,A0); PROC(17,A1); PROC(18,A2); PROC(19,A3);
    PROC(20,A4); PROC(21,A5); PROC(22,A6); PROC(23,A7);
    A0=LD(32); A1=LD(33); A2=LD(34); A3=LD(35);
    A4=LD(36); A5=LD(37); A6=LD(38); A7=LDC(39);

    PROC(24,B0); PROC(25,B1); PROC(26,B2); PROC(27,B3);
    PROC(28,B4); PROC(29,B5); PROC(30,B6); PROC(31,B7);

    PROC(32,A0); PROC(33,A1); PROC(34,A2); PROC(35,A3);
    PROC(36,A4); PROC(37,A5); PROC(38,A6); PROCM(39,A7);

    // ---- wave-reduce: exactly one lane holds nonzero (pos 0 also correct) ----
    int pos = pacc;
    #pragma unroll
    for (int off = 32; off; off >>= 1) pos += __shfl_xor(pos, off);

    const float s_pos = irow[pos];             // 1 dependent line, broadcast

    // ---- progressive first-accept: 16 -> 64 -> 48 trials ----
    int   first = -1;
    float s_neg = 0.0f;
    const unsigned long long bA =
        __ballot(1.0f + sA - s_pos >= 0.0f) & 0xFFFFull;      // trials 0..15
    if (bA) {
        first = __ffsll(bA) - 1;
        s_neg = __shfl(sA, first);
    } else {
        const int   cB = nrow[16 + lane];                     // trials 16..79
        const float sB = irow[cB];
        const unsigned long long bB = __ballot(1.0f + sB - s_pos >= 0.0f);
        if (bB) {
            const int f = __ffsll(bB) - 1;
            first = 16 + f;
            s_neg = __shfl(sB, f);
        } else {
            const int   iC = 80 + lane;                       // trials 80..127
            const int   cC = nrow[iC < Tc ? iC : Tc - 1];
            const float sC = irow[cC];
            const unsigned long long bC =
                __ballot(1.0f + sC - s_pos >= 0.0f) & ((1ull << 48) - 1);
            if (bC) {
                const int f = __ffsll(bC) - 1;
                first = 80 + f;
                s_neg = __shfl(sC, f);
            }
        }
    }

    float contrib = 0.0f;
    if (first >= 0) {
        const int   nt = first + 1;
        const float L  = logf((float)((Yc - 1) / nt));        // floor-div, log
        contrib = L * (1.0f - s_pos + s_neg);
    }
    if (lane == 0) partial[row] = contrib;
}

__global__ __launch_bounds__(256) void reduce_partials(
        const float* __restrict__ partial,
        float* __restrict__ out, int n) {
    float s = 0.0f;
    for (int i = threadIdx.x; i < n; i += 256) s += partial[i];
    #pragma unroll
    for (int off = 32; off; off >>= 1) s += __shfl_down(s, off);
    __shared__ float ws[4];
    if ((threadIdx.x & 63) == 0) ws[threadIdx.x >> 6] = s;
    __syncthreads();
    if (threadIdx.x == 0) out[0] = ws[0] + ws[1] + ws[2] + ws[3];
}

extern "C" void kernel_launch(void* const* d_in, const int* in_sizes, int n_in,
                              void* d_out, int out_size, void* d_ws, size_t ws_size,
                              hipStream_t stream) {
    const float* input  = (const float*)d_in[0];
    const float* target = (const float*)d_in[1];
    const int*   neg    = (const int*)d_in[2];
    float* out     = (float*)d_out;
    float* partial = (float*)d_ws;             // B floats

    const int B    = in_sizes[2] / Tc;         // 4096
    const int nblk = (B + 3) / 4;              // 1024 blocks, 1 wave per row

    warp_fused_kernel<<<nblk, 256, 0, stream>>>(input, target, neg, partial, B);
    reduce_partials<<<1, 256, 0, stream>>>(partial, out, B);
}

// Round 8
// 278.064 us; speedup vs baseline: 1.0732x; 1.0732x over previous
//
#include <hip/hip_runtime.h>

// WARP loss: B=4096 rows, Y=10000 labels, T=128 negative-candidate trials.
// input [B,Y] f32, target [B,Y] f32 (one-hot), neg_candidates [B,T] i32.
// out[0] = sum over rows of log((Y-1)/num_trials) * (1 - s_pos + s_neg),
// num_trials = 1 + first t with 1 + s_neg_t - s_pos >= 0 (0 contribution if none).
//
// Byte-minimal design (R0-R7 evidence: reads cap ~2.4 TB/s regardless of
// structure; time ~ fixed + bytes/BW, so minimize bytes):
//   - one wave per row; 1 KB (1-group) scan chunks, ping-pong depth-2,
//     refill AFTER check -> overshoot <= ~2 KB; E[target read] ~ 22 KB/row
//   - non-temporal loads on the target stream (read-once, no cache pollute)
//   - stage-A = first 8 candidates (reject-all-8 prob ~1e-5); progressive
//     widening 8 -> 64 -> 56 preserves exact first-accept semantics
//   - per-row partials in d_ws; 1-block reduce writes out[0] (overwrites
//     harness poison; no memset, no global atomics).

constexpr int Yc = 10000;
constexpr int Tc = 128;
constexpr int R4 = 2500;   // uint4 per row (40 KB, 16B-aligned per row)
constexpr int NG = 40;     // 1 KB groups per row (64 lanes x 16 B)

using u32x4 = unsigned int __attribute__((ext_vector_type(4)));

__global__ __launch_bounds__(256) void warp_fused_kernel(
        const float* __restrict__ input,
        const float* __restrict__ target,
        const int*   __restrict__ neg,
        float* __restrict__ partial,
        int B) {
    const int wave = threadIdx.x >> 6;
    const int lane = threadIdx.x & 63;
    const int row  = blockIdx.x * 4 + wave;
    if (row >= B) return;                      // no barriers below: safe

    const int*   nrow = neg + row * Tc;
    const float* irow = input + (size_t)row * Yc;
    const u32x4* trow = reinterpret_cast<const u32x4*>(target + (size_t)row * Yc);

    auto LDG = [&](int g) -> u32x4 {           // group g, lane's 16 B, NT load
        int idx = g * 64 + lane;
        if (idx >= R4) idx = R4 - 1;           // clamp: duplicate last element
        return __builtin_nontemporal_load(&trow[idx]);
    };
    // min one-hot element index within one group, or -1 (wave-uniform)
    auto CHK = [&](int g, const u32x4& v) -> int {
        const unsigned nz = v[0] | v[1] | v[2] | v[3];
        if (!__any(nz != 0)) return -1;
        int mine = 0x7fffffff;
        if (nz) {
            int idx = g * 64 + lane; if (idx >= R4) idx = R4 - 1;
            int sub = v[0] ? 0 : (v[1] ? 1 : (v[2] ? 2 : 3));
            mine = 4 * idx + sub;
        }
        #pragma unroll
        for (int off = 32; off; off >>= 1)
            mine = min(mine, __shfl_xor(mine, off));
        return mine;
    };

    // ---- prologue: stage-A neg (1 line) + 8 gather lines fly under scan ----
    const int cA = nrow[lane & 7];             // trials 0..7 (x8 dup)
    u32x4 A = LDG(0), Bv = LDG(1);
    const float sA = irow[cA];                 // waits only on cA; A,Bv in flight

    // ---- early-exit scan, 1 KB ping-pong, refill after check ----
    int posIdx = -1;
    for (int g = 0; g < NG; g += 2) {
        posIdx = CHK(g, A);                    // waits A only
        if (posIdx >= 0) break;
        if (g + 2 < NG) A = LDG(g + 2);
        posIdx = CHK(g + 1, Bv);               // waits Bv only
        if (posIdx >= 0) break;
        if (g + 3 < NG) Bv = LDG(g + 3);
    }

    const float s_pos = (posIdx >= 0) ? irow[posIdx] : 0.0f;  // 1 line, bcast

    // ---- progressive first-accept: 8 -> 64 -> 56 trials ----
    int   first = -1;
    float s_neg = 0.0f;
    const unsigned long long bA =
        __ballot(1.0f + sA - s_pos >= 0.0f) & 0xFFull;        // trials 0..7
    if (bA) {
        first = __ffsll(bA) - 1;
        s_neg = __shfl(sA, first);
    } else {
        const int   cB = nrow[8 + lane];                      // trials 8..71
        const float sB = irow[cB];
        const unsigned long long bB = __ballot(1.0f + sB - s_pos >= 0.0f);
        if (bB) {
            const int f = __ffsll(bB) - 1;
            first = 8 + f;
            s_neg = __shfl(sB, f);
        } else {
            const int   iC = 72 + lane;                       // trials 72..127
            const int   cC = nrow[iC < Tc ? iC : Tc - 1];
            const float sC = irow[cC];
            const unsigned long long bC =
                __ballot(1.0f + sC - s_pos >= 0.0f) & ((1ull << 56) - 1);
            if (bC) {
                const int f = __ffsll(bC) - 1;
                first = 72 + f;
                s_neg = __shfl(sC, f);
            }
        }
    }

    float contrib = 0.0f;
    if (posIdx >= 0 && first >= 0) {
        const int   nt = first + 1;
        const float L  = logf((float)((Yc - 1) / nt));        // floor-div, log
        contrib = L * (1.0f - s_pos + s_neg);
    }
    if (lane == 0) partial[row] = contrib;
}

__global__ __launch_bounds__(256) void reduce_partials(
        const float* __restrict__ partial,
        float* __restrict__ out, int n) {
    float s = 0.0f;
    for (int i = threadIdx.x; i < n; i += 256) s += partial[i];
    #pragma unroll
    for (int off = 32; off; off >>= 1) s += __shfl_down(s, off);
    __shared__ float ws[4];
    if ((threadIdx.x & 63) == 0) ws[threadIdx.x >> 6] = s;
    __syncthreads();
    if (threadIdx.x == 0) out[0] = ws[0] + ws[1] + ws[2] + ws[3];
}

extern "C" void kernel_launch(void* const* d_in, const int* in_sizes, int n_in,
                              void* d_out, int out_size, void* d_ws, size_t ws_size,
                              hipStream_t stream) {
    const float* input  = (const float*)d_in[0];
    const float* target = (const float*)d_in[1];
    const int*   neg    = (const int*)d_in[2];
    float* out     = (float*)d_out;
    float* partial = (float*)d_ws;             // B floats

    const int B    = in_sizes[2] / Tc;         // 4096
    const int nblk = (B + 3) / 4;              // 1024 blocks, 1 wave per row

    warp_fused_kernel<<<nblk, 256, 0, stream>>>(input, target, neg, partial, B);
    reduce_partials<<<1, 256, 0, stream>>>(partial, out, B);
}